// Round 5
// baseline (190.806 us; speedup 1.0000x reference)
//
#include <hip/hip_runtime.h>
#include <hip/hip_bf16.h>
#include <math.h>

#define BB 32
#define NN 512

typedef short bf16x8 __attribute__((ext_vector_type(8)));
typedef float f32x4 __attribute__((ext_vector_type(4)));

static __device__ __forceinline__ unsigned short f2bf(float v) {
    __hip_bfloat16 h = __float2bfloat16(v);
    return __builtin_bit_cast(unsigned short, h);
}
static __device__ __forceinline__ float bf2f(unsigned short u) {
    __hip_bfloat16 h = __builtin_bit_cast(__hip_bfloat16, u);
    return __bfloat162float(h);
}

// ============ W^T bf16 hi/lo prep, XOR-swizzled per 64-k chunk ==============
// WT[n][c*64 + p*8 + e] = bf(W[(c*8+gl)*8... ]) with p = gl ^ (n&7)
__global__ __launch_bounds__(256) void k_wt_prep(
    const float* __restrict__ W, int KT,
    unsigned short* __restrict__ Wh, unsigned short* __restrict__ Wl)
{
    int id = blockIdx.x * 256 + threadIdx.x;
    int n = id & 63, gabs = id >> 6;
    if (gabs >= (KT >> 3)) return;
    int c = gabs >> 3, gl = gabs & 7;
    int p = gl ^ (n & 7);
    bf16x8 hv, lv;
#pragma unroll
    for (int e = 0; e < 8; ++e) {
        float v = W[(size_t)(gabs * 8 + e) * 64 + n];
        unsigned short hb = f2bf(v);
        hv[e] = (short)hb;
        lv[e] = (short)f2bf(v - bf2f(hb));
    }
    size_t g = (size_t)n * KT + c * 64 + p * 8;
    *(bf16x8*)(Wh + g) = hv;
    *(bf16x8*)(Wl + g) = lv;
}

// ============ shared epilogue: 16x66 ctile -> s/d heads + swizzled hpT ======
static __device__ __forceinline__ void epi_sd_hpt(
    const float* ctile, const float* asd_f, int row0, int t,
    float* __restrict__ s, float* __restrict__ d,
    unsigned short* __restrict__ hpTh, unsigned short* __restrict__ hpTl)
{
    if (t < 128) {
        int rr = t >> 3, h = t & 7;
        float sv = 0.f, dv = 0.f;
#pragma unroll
        for (int f = 0; f < 64; ++f) {
            float hv = ctile[rr * 66 + f];
            sv = fmaf(hv, asd_f[f * 8 + h], sv);
            dv = fmaf(hv, asd_f[512 + f * 8 + h], dv);
        }
        s[(size_t)(row0 + rr) * 8 + h] = sv;
        d[(size_t)(row0 + rr) * 8 + h] = dv;
    } else {
        int t2 = t - 128;
        int f = t2 >> 1, jl = (t2 & 1) * 8;
        bf16x8 hv, lv;
#pragma unroll
        for (int e = 0; e < 8; ++e) {
            float v = ctile[(jl + e) * 66 + f];
            unsigned short hb = f2bf(v);
            hv[e] = (short)hb;
            lv[e] = (short)f2bf(v - bf2f(hb));
        }
        int b = row0 >> 9, jb = row0 & 511;
        int jj = jb + jl;
        int cch = jj >> 6, p = ((jj >> 3) & 7) ^ (f & 7);
        size_t g = ((size_t)b * 64 + f) * 512 + cch * 64 + p * 8;
        *(bf16x8*)(hpTh + g) = hv;
        *(bf16x8*)(hpTl + g) = lv;
    }
}

// ============ Layer-0 GEMM via MFMA: 16 rows/block, K=64, grid 1024 =========
__global__ __launch_bounds__(256) void k_gemm0(
    const float* __restrict__ x,
    const unsigned short* __restrict__ W0Th, const unsigned short* __restrict__ W0Tl,
    const float* __restrict__ a_src, const float* __restrict__ a_dst,
    float* __restrict__ s, float* __restrict__ d,
    unsigned short* __restrict__ hpTh, unsigned short* __restrict__ hpTl)
{
    __shared__ short Ah[16 * 64], Al[16 * 64];
    __shared__ short Bh[64 * 64], Bl[64 * 64];
    __shared__ float ctile[16 * 66];
    __shared__ float asd_f[1024];

    int t = threadIdx.x;
    int row0 = blockIdx.x * 16;

    ((float4*)asd_f)[t] = (t < 128) ? ((const float4*)a_src)[t]
                                    : ((const float4*)a_dst)[t - 128];
    {   // stage B (pre-swizzled)
        int n = t >> 2, gp = (t & 3) * 2;
#pragma unroll
        for (int u = 0; u < 2; ++u) {
            *(uint4*)&Bh[n * 64 + (gp + u) * 8] = *(const uint4*)(W0Th + (size_t)n * 64 + (gp + u) * 8);
            *(uint4*)&Bl[n * 64 + (gp + u) * 8] = *(const uint4*)(W0Tl + (size_t)n * 64 + (gp + u) * 8);
        }
    }
    if (t < 128) {  // stage+convert A
        int row = t >> 3, g = t & 7;
        const float4* src = (const float4*)(x + (size_t)(row0 + row) * 64 + g * 8);
        float4 v0 = src[0], v1 = src[1];
        float vv[8] = {v0.x, v0.y, v0.z, v0.w, v1.x, v1.y, v1.z, v1.w};
        bf16x8 hv, lv;
#pragma unroll
        for (int e = 0; e < 8; ++e) {
            unsigned short hb = f2bf(vv[e]);
            hv[e] = (short)hb;
            lv[e] = (short)f2bf(vv[e] - bf2f(hb));
        }
        int p = g ^ (row & 7);
        *(bf16x8*)&Ah[row * 64 + p * 8] = hv;
        *(bf16x8*)&Al[row * 64 + p * 8] = lv;
    }
    __syncthreads();

    int lane = t & 63, w = t >> 6, cn = lane & 15, rq = lane >> 4;
    f32x4 acc, acc2;
#pragma unroll
    for (int e = 0; e < 4; ++e) { acc[e] = 0.f; acc2[e] = 0.f; }

#pragma unroll
    for (int ks = 0; ks < 2; ++ks) {
        int pa = ((ks * 4 + rq) ^ (cn & 7)) * 8;
        bf16x8 ah = *(const bf16x8*)&Ah[cn * 64 + pa];
        bf16x8 al = *(const bf16x8*)&Al[cn * 64 + pa];
        int nn = w * 16 + cn;
        int pb = ((ks * 4 + rq) ^ (cn & 7)) * 8;   // nn&7 == cn&7
        bf16x8 bh = *(const bf16x8*)&Bh[nn * 64 + pb];
        bf16x8 bl = *(const bf16x8*)&Bl[nn * 64 + pb];
        acc  = __builtin_amdgcn_mfma_f32_16x16x32_bf16(ah, bh, acc, 0, 0, 0);
        acc2 = __builtin_amdgcn_mfma_f32_16x16x32_bf16(ah, bl, acc2, 0, 0, 0);
        acc2 = __builtin_amdgcn_mfma_f32_16x16x32_bf16(al, bh, acc2, 0, 0, 0);
    }
#pragma unroll
    for (int r = 0; r < 4; ++r)
        ctile[(rq * 4 + r) * 66 + w * 16 + cn] = acc[r] + acc2[r];
    __syncthreads();
    epi_sd_hpt(ctile, asd_f, row0, t, s, d, hpTh, hpTl);
}

// ============ Layer-1 GEMM via MFMA: 16 rows/block, K=512, grid 1024 ========
// A from pre-split bf16 x1 (straight copy), B from pre-swizzled W1T.
__global__ __launch_bounds__(256) void k_gemm1(
    const unsigned short* __restrict__ x1h, const unsigned short* __restrict__ x1l,
    const unsigned short* __restrict__ W1Th, const unsigned short* __restrict__ W1Tl,
    const float* __restrict__ a_src, const float* __restrict__ a_dst,
    float* __restrict__ s, float* __restrict__ d,
    unsigned short* __restrict__ hpTh, unsigned short* __restrict__ hpTl)
{
    __shared__ short Ah[16 * 64], Al[16 * 64];
    __shared__ short Bh[64 * 64], Bl[64 * 64];
    __shared__ float ctile[16 * 66];
    __shared__ float asd_f[1024];

    int t = threadIdx.x;
    int row0 = blockIdx.x * 16;
    ((float4*)asd_f)[t] = (t < 128) ? ((const float4*)a_src)[t]
                                    : ((const float4*)a_dst)[t - 128];

    int ar = (t & 127) >> 3, ag = t & 7;
    const unsigned short* asrc = (t < 128) ? x1h : x1l;
    short* adst = (t < 128) ? Ah : Al;
    int bn = t >> 2, bg0 = (t & 3) * 2;

    uint4 ra, rb0, rb1, rb2, rb3;
    ra  = *(const uint4*)(asrc + (size_t)(row0 + ar) * 512 + ag * 8);
    rb0 = *(const uint4*)(W1Th + (size_t)bn * 512 + (bg0 + 0) * 8);
    rb1 = *(const uint4*)(W1Th + (size_t)bn * 512 + (bg0 + 1) * 8);
    rb2 = *(const uint4*)(W1Tl + (size_t)bn * 512 + (bg0 + 0) * 8);
    rb3 = *(const uint4*)(W1Tl + (size_t)bn * 512 + (bg0 + 1) * 8);

    int lane = t & 63, w = t >> 6, cn = lane & 15, rq = lane >> 4;
    f32x4 acc, acc2;
#pragma unroll
    for (int e = 0; e < 4; ++e) { acc[e] = 0.f; acc2[e] = 0.f; }

    for (int kc = 0; kc < 8; ++kc) {
        *(uint4*)&adst[ar * 64 + ag * 8] = ra;
        *(uint4*)&Bh[bn * 64 + (bg0 + 0) * 8] = rb0;
        *(uint4*)&Bh[bn * 64 + (bg0 + 1) * 8] = rb1;
        *(uint4*)&Bl[bn * 64 + (bg0 + 0) * 8] = rb2;
        *(uint4*)&Bl[bn * 64 + (bg0 + 1) * 8] = rb3;
        __syncthreads();
        if (kc < 7) {
            int k0 = (kc + 1) * 64;
            ra  = *(const uint4*)(asrc + (size_t)(row0 + ar) * 512 + k0 + ag * 8);
            rb0 = *(const uint4*)(W1Th + (size_t)bn * 512 + k0 + (bg0 + 0) * 8);
            rb1 = *(const uint4*)(W1Th + (size_t)bn * 512 + k0 + (bg0 + 1) * 8);
            rb2 = *(const uint4*)(W1Tl + (size_t)bn * 512 + k0 + (bg0 + 0) * 8);
            rb3 = *(const uint4*)(W1Tl + (size_t)bn * 512 + k0 + (bg0 + 1) * 8);
        }
#pragma unroll
        for (int ks = 0; ks < 2; ++ks) {
            int pa = ((ks * 4 + rq) ^ (cn & 7)) * 8;
            bf16x8 ah = *(const bf16x8*)&Ah[cn * 64 + pa];
            bf16x8 al = *(const bf16x8*)&Al[cn * 64 + pa];
            int nn = w * 16 + cn;
            bf16x8 bh = *(const bf16x8*)&Bh[nn * 64 + pa];
            bf16x8 bl = *(const bf16x8*)&Bl[nn * 64 + pa];
            acc  = __builtin_amdgcn_mfma_f32_16x16x32_bf16(ah, bh, acc, 0, 0, 0);
            acc2 = __builtin_amdgcn_mfma_f32_16x16x32_bf16(ah, bl, acc2, 0, 0, 0);
            acc2 = __builtin_amdgcn_mfma_f32_16x16x32_bf16(al, bh, acc2, 0, 0, 0);
        }
        __syncthreads();
    }
#pragma unroll
    for (int r = 0; r < 4; ++r)
        ctile[(rq * 4 + r) * 66 + w * 16 + cn] = acc[r] + acc2[r];
    __syncthreads();
    epi_sd_hpt(ctile, asd_f, row0, t, s, d, hpTh, hpTl);
}

// ============ MFMA attention v3: double-buffered, 1 barrier/chunk ==========
// mode 0: ELU, writes x1 as swizzled bf16 hi/lo. mode 1: head-mean fp32.
__global__ __launch_bounds__(256, 4) void k_attn_mfma(
    const float* __restrict__ adj, const float* __restrict__ s,
    const float* __restrict__ d,
    const unsigned short* __restrict__ hpTh,
    const unsigned short* __restrict__ hpTl,
    unsigned short* __restrict__ o_h, unsigned short* __restrict__ o_l,
    float* __restrict__ o_f, int mode)
{
    __shared__ short hT[2][8192];              // 16KB each buffer
    __shared__ float dT[2][8 * 68];
    __shared__ unsigned long long maskL[2][16];
    __shared__ float inv[128];
    float* red = (float*)&hT[0][0];

    int blk = blockIdx.x;
    int vb = ((blk & 7) << 7) | (blk >> 3);    // XCD swizzle
    int b = vb >> 5, i0 = (vb & 31) << 4;
    int t = threadIdx.x, lane = t & 63, w = t >> 6;
    int cn = lane & 15, rq = lane >> 4;
    int h0 = w * 2, h1 = h0 + 1;

    float sv0 = s[((size_t)b * NN + i0 + cn) * 8 + h0];
    float sv1 = s[((size_t)b * NN + i0 + cn) * 8 + h1];

    const float* adjb = adj + ((size_t)b * NN + i0) * NN;
    const unsigned short* hbh = hpTh + (size_t)b * 64 * 512;
    const unsigned short* hbl = hpTl + (size_t)b * 64 * 512;

    // ---- prologue: stage chunk 0 into buffer 0
#pragma unroll
    for (int pp = 0; pp < 4; ++pp) {
        int row = pp * 4 + w;
        float a = adjb[(size_t)row * NN + lane];
        bool bit = (a != 0.f) || ((i0 + row) == lane);
        unsigned long long m = __ballot(bit);
        if (lane == 0) maskL[0][row] = m;
    }
    if (t < 128) {
        int j = t >> 1, h4 = (t & 1) * 4;
        float4 dv = *(const float4*)(d + ((size_t)b * NN + j) * 8 + h4);
        dT[0][(h4 + 0) * 68 + j] = dv.x;
        dT[0][(h4 + 1) * 68 + j] = dv.y;
        dT[0][(h4 + 2) * 68 + j] = dv.z;
        dT[0][(h4 + 3) * 68 + j] = dv.w;
    }
#pragma unroll
    for (int u = 0; u < 2; ++u) {
        int idx = t + u * 256;
        int f = idx >> 3, g = idx & 7;
        *(uint4*)&hT[0][f * 64 + g * 8]        = *(const uint4*)(hbh + (size_t)f * 512 + g * 8);
        *(uint4*)&hT[0][4096 + f * 64 + g * 8] = *(const uint4*)(hbl + (size_t)f * 512 + g * 8);
    }
    __syncthreads();

    f32x4 acc[2][4];
#pragma unroll
    for (int hh = 0; hh < 2; ++hh)
#pragma unroll
        for (int ft = 0; ft < 4; ++ft)
#pragma unroll
            for (int e = 0; e < 4; ++e) acc[hh][ft][e] = 0.f;
    float rs0 = 0.f, rs1 = 0.f;

    for (int jcx = 0; jcx < 8; ++jcx) {
        int cur = jcx & 1, nxt = cur ^ 1;
        int jcn = (jcx + 1) * 64;
        bool pf = jcx < 7;
        float pa[4];
        float4 pd;
        uint4 ph0, ph1, pl0, pl1;
        if (pf) {
#pragma unroll
            for (int pp = 0; pp < 4; ++pp)
                pa[pp] = adjb[(size_t)(pp * 4 + w) * NN + jcn + lane];
            if (t < 128) {
                int j = t >> 1, h4 = (t & 1) * 4;
                pd = *(const float4*)(d + ((size_t)b * NN + jcn + j) * 8 + h4);
            }
            {
                int f0 = t >> 3, g0 = t & 7;
                int f1 = (t + 256) >> 3, g1 = t & 7;
                ph0 = *(const uint4*)(hbh + (size_t)f0 * 512 + jcn + g0 * 8);
                pl0 = *(const uint4*)(hbl + (size_t)f0 * 512 + jcn + g0 * 8);
                ph1 = *(const uint4*)(hbh + (size_t)f1 * 512 + jcn + g1 * 8);
                pl1 = *(const uint4*)(hbl + (size_t)f1 * 512 + jcn + g1 * 8);
            }
        }

        // ---- P-build in A-fragment registers (buffer cur)
        unsigned long long mk = maskL[cur][cn];
        bf16x8 aA[2], aB[2];
#pragma unroll
        for (int ks = 0; ks < 2; ++ks) {
            int shift = ks * 32 + rq * 8;
            unsigned int mb = (unsigned int)(mk >> shift) & 0xffu;
            const float* dp0 = &dT[cur][h0 * 68 + shift];
            const float* dp1 = &dT[cur][h1 * 68 + shift];
            float4 da0 = *(const float4*)dp0, da1 = *(const float4*)(dp0 + 4);
            float4 db0 = *(const float4*)dp1, db1 = *(const float4*)(dp1 + 4);
            float dd0[8] = {da0.x, da0.y, da0.z, da0.w, da1.x, da1.y, da1.z, da1.w};
            float dd1[8] = {db0.x, db0.y, db0.z, db0.w, db1.x, db1.y, db1.z, db1.w};
#pragma unroll
            for (int e = 0; e < 8; ++e) {
                bool mbit = (mb >> e) & 1;
                float e0 = sv0 + dd0[e];
                e0 = fmaxf(e0, 0.2f * e0);
                float p0 = (mbit && e0 != 0.f) ? __expf(e0) : 0.f;
                rs0 += p0;
                float e1 = sv1 + dd1[e];
                e1 = fmaxf(e1, 0.2f * e1);
                float p1 = (mbit && e1 != 0.f) ? __expf(e1) : 0.f;
                rs1 += p1;
                aA[ks][e] = (short)f2bf(p0);
                aB[ks][e] = (short)f2bf(p1);
            }
        }
        // ---- MFMA on buffer cur
#pragma unroll
        for (int ks = 0; ks < 2; ++ks)
#pragma unroll
            for (int ft = 0; ft < 4; ++ft) {
                int f = ft * 16 + cn;
                int pb = ((ks * 4 + rq) ^ (f & 7)) * 8;
                bf16x8 bh = *(const bf16x8*)&hT[cur][f * 64 + pb];
                bf16x8 bl = *(const bf16x8*)&hT[cur][4096 + f * 64 + pb];
                acc[0][ft] = __builtin_amdgcn_mfma_f32_16x16x32_bf16(aA[ks], bh, acc[0][ft], 0, 0, 0);
                acc[0][ft] = __builtin_amdgcn_mfma_f32_16x16x32_bf16(aA[ks], bl, acc[0][ft], 0, 0, 0);
                acc[1][ft] = __builtin_amdgcn_mfma_f32_16x16x32_bf16(aB[ks], bh, acc[1][ft], 0, 0, 0);
                acc[1][ft] = __builtin_amdgcn_mfma_f32_16x16x32_bf16(aB[ks], bl, acc[1][ft], 0, 0, 0);
            }

        // ---- commit prefetched chunk to buffer nxt
        if (pf) {
#pragma unroll
            for (int pp = 0; pp < 4; ++pp) {
                int row = pp * 4 + w;
                bool bit = (pa[pp] != 0.f) || ((i0 + row) == (jcn + lane));
                unsigned long long m = __ballot(bit);
                if (lane == 0) maskL[nxt][row] = m;
            }
            if (t < 128) {
                int j = t >> 1, h4 = (t & 1) * 4;
                dT[nxt][(h4 + 0) * 68 + j] = pd.x;
                dT[nxt][(h4 + 1) * 68 + j] = pd.y;
                dT[nxt][(h4 + 2) * 68 + j] = pd.z;
                dT[nxt][(h4 + 3) * 68 + j] = pd.w;
            }
            {
                int f0 = t >> 3, g0 = t & 7;
                int f1 = (t + 256) >> 3;
                *(uint4*)&hT[nxt][f0 * 64 + g0 * 8]        = ph0;
                *(uint4*)&hT[nxt][4096 + f0 * 64 + g0 * 8] = pl0;
                *(uint4*)&hT[nxt][f1 * 64 + g0 * 8]        = ph1;
                *(uint4*)&hT[nxt][4096 + f1 * 64 + g0 * 8] = pl1;
            }
        }
        __syncthreads();
    }

    // ---- rowsums -> inverse
    rs0 += __shfl_xor(rs0, 16); rs0 += __shfl_xor(rs0, 32);
    rs1 += __shfl_xor(rs1, 16); rs1 += __shfl_xor(rs1, 32);
    if (rq == 0) {
        inv[h0 * 16 + cn] = 1.0f / rs0;
        inv[h1 * 16 + cn] = 1.0f / rs1;
    }
    __syncthreads();

    if (mode == 0) {
#pragma unroll
        for (int hh = 0; hh < 2; ++hh) {
            int h = h0 + hh;
#pragma unroll
            for (int ft = 0; ft < 4; ++ft)
#pragma unroll
                for (int r = 0; r < 4; ++r) {
                    int il = rq * 4 + r;
                    float v = acc[hh][ft][r] * inv[h * 16 + il];
                    v = v > 0.f ? v : __expf(v) - 1.f;   // ELU
                    int g = ft * 2 + (cn >> 3);
                    int p = g ^ (il & 7);
                    size_t addr = ((size_t)b * NN + i0 + il) * 512 + h * 64 + p * 8 + (cn & 7);
                    unsigned short hb = f2bf(v);
                    o_h[addr] = hb;
                    o_l[addr] = f2bf(v - bf2f(hb));
                }
        }
    } else {
#pragma unroll
        for (int ft = 0; ft < 4; ++ft)
#pragma unroll
            for (int r = 0; r < 4; ++r) {
                int il = rq * 4 + r;
                float v = acc[0][ft][r] * inv[h0 * 16 + il]
                        + acc[1][ft][r] * inv[h1 * 16 + il];
                red[(w * 16 + il) * 64 + ft * 16 + cn] = v;
            }
        __syncthreads();
#pragma unroll
        for (int u = 0; u < 4; ++u) {
            int idx = t + u * 256;
            int il = idx >> 6, f = idx & 63;
            float sum = red[il * 64 + f] + red[(16 + il) * 64 + f]
                      + red[(32 + il) * 64 + f] + red[(48 + il) * 64 + f];
            o_f[((size_t)b * NN + i0 + il) * 64 + f] = sum * 0.125f;
        }
    }
}

extern "C" void kernel_launch(void* const* d_in, const int* in_sizes, int n_in,
                              void* d_out, int out_size, void* d_ws, size_t ws_size,
                              hipStream_t stream) {
    const float* x      = (const float*)d_in[0];
    const float* adj    = (const float*)d_in[1];
    const float* W0     = (const float*)d_in[4];
    const float* a_src0 = (const float*)d_in[5];
    const float* a_dst0 = (const float*)d_in[6];
    const float* W1     = (const float*)d_in[7];
    const float* a_src1 = (const float*)d_in[8];
    const float* a_dst1 = (const float*)d_in[9];
    float* out = (float*)d_out;

    float* ws = (float*)d_ws;
    const size_t R = (size_t)BB * NN;        // 16384 rows
    float* s0 = ws;                          // R*8
    float* d0 = s0 + R * 8;
    float* s1 = d0 + R * 8;
    float* d1 = s1 + R * 8;
    unsigned short* x1h  = (unsigned short*)(d1 + R * 8);       // R*512 each
    unsigned short* x1l  = x1h + R * 512;
    unsigned short* hp0h = x1l + R * 512;                        // B*64*512 each
    unsigned short* hp0l = hp0h + (size_t)BB * 64 * NN;
    unsigned short* hp1h = hp0l + (size_t)BB * 64 * NN;
    unsigned short* hp1l = hp1h + (size_t)BB * 64 * NN;
    unsigned short* W0Th = hp1l + (size_t)BB * 64 * NN;          // 64*64 each
    unsigned short* W0Tl = W0Th + (size_t)64 * 64;
    unsigned short* W1Th = W0Tl + (size_t)64 * 64;               // 64*512 each
    unsigned short* W1Tl = W1Th + (size_t)64 * 512;

    k_wt_prep<<<2, 256, 0, stream>>>(W0, 64, W0Th, W0Tl);
    k_wt_prep<<<16, 256, 0, stream>>>(W1, 512, W1Th, W1Tl);
    k_gemm0<<<1024, 256, 0, stream>>>(x, W0Th, W0Tl, a_src0, a_dst0, s0, d0, hp0h, hp0l);
    k_attn_mfma<<<1024, 256, 0, stream>>>(adj, s0, d0, hp0h, hp0l, x1h, x1l, nullptr, 0);
    k_gemm1<<<1024, 256, 0, stream>>>(x1h, x1l, W1Th, W1Tl, a_src1, a_dst1, s1, d1, hp1h, hp1l);
    k_attn_mfma<<<1024, 256, 0, stream>>>(adj, s1, d1, hp1h, hp1l, nullptr, nullptr, out, 1);
}